// Round 12
// baseline (2034.729 us; speedup 1.0000x reference)
//
#include <hip/hip_runtime.h>

// Problem constants
#define SEQ   2048
#define NHEAD 16
#define NKV   4
#define HDIM  128
#define NB    4
// qkv_raw row layout: [qg 0..4095 | k 4096..4607 | v 4608..5119]
#define QKVW  5120

typedef unsigned short u16;
typedef unsigned int   u32;
typedef __bf16 v8bf __attribute__((ext_vector_type(8)));
typedef float  v4f  __attribute__((ext_vector_type(4)));

__device__ __forceinline__ u16 f2bf(float f) {
  u32 u = __float_as_uint(f);
  u += 0x7fffu + ((u >> 16) & 1u);
  return (u16)(u >> 16);
}
__device__ __forceinline__ float bf2f(u16 b) {
  return __uint_as_float(((u32)b) << 16);
}

// Async global->LDS DMA, 16B per lane. LDS dest must be linear in lane order
// (wave-uniform base + lane*16).
__device__ __forceinline__ void gld_lds16(const u16* g, u16* l) {
  __builtin_amdgcn_global_load_lds(
      (const __attribute__((address_space(1))) u32*)(unsigned long long)(uintptr_t)g,
      (__attribute__((address_space(3))) u32*)(u32)(uintptr_t)l,
      16, 0, 0);
}

// ---------------------------------------------------------------------------
// Device bodies for the fused prep kernels
// ---------------------------------------------------------------------------
__device__ __forceinline__ void conv_body(const float* __restrict__ s,
                                          u16* __restrict__ d, int blk, int t) {
  size_t i = ((size_t)blk * 256 + t) * 8;
  float4 a = *(const float4*)(s + i);
  float4 b = *(const float4*)(s + i + 4);
  uint4 o;
  o.x = (u32)f2bf(a.x) | ((u32)f2bf(a.y) << 16);
  o.y = (u32)f2bf(a.z) | ((u32)f2bf(a.w) << 16);
  o.z = (u32)f2bf(b.x) | ((u32)f2bf(b.y) << 16);
  o.w = (u32)f2bf(b.z) | ((u32)f2bf(b.w) << 16);
  *(uint4*)(d + i) = o;
}

// fp32 src -> bf16 transposed dst: dst[c*R + r] = bf16(src[r*C + c])
__device__ __forceinline__ void tw_body(const float* __restrict__ src,
                                        u16* __restrict__ dst, int R, int C,
                                        int bx, int by, int t,
                                        u16 (*tile)[80]) {
  int r0 = by * 64, c0 = bx * 64;
  int rr = t >> 2, cc = (t & 3) * 16;
  const float* sp = src + (size_t)(r0 + rr) * C + c0 + cc;
  float4 f0 = *(const float4*)sp;
  float4 f1 = *(const float4*)(sp + 4);
  float4 f2 = *(const float4*)(sp + 8);
  float4 f3 = *(const float4*)(sp + 12);
  u16* tp = &tile[rr][cc];
  tp[0] = f2bf(f0.x);  tp[1] = f2bf(f0.y);  tp[2] = f2bf(f0.z);  tp[3] = f2bf(f0.w);
  tp[4] = f2bf(f1.x);  tp[5] = f2bf(f1.y);  tp[6] = f2bf(f1.z);  tp[7] = f2bf(f1.w);
  tp[8] = f2bf(f2.x);  tp[9] = f2bf(f2.y);  tp[10] = f2bf(f2.z); tp[11] = f2bf(f2.w);
  tp[12] = f2bf(f3.x); tp[13] = f2bf(f3.y); tp[14] = f2bf(f3.z); tp[15] = f2bf(f3.w);
  __syncthreads();
  int cr = t >> 2, rc = (t & 3) * 16;
  u32 pk[8];
#pragma unroll
  for (int i = 0; i < 8; i++) {
    u32 lo = tile[rc + 2 * i][cr];
    u32 hi = tile[rc + 2 * i + 1][cr];
    pk[i] = lo | (hi << 16);
  }
  u16* dp = dst + (size_t)(c0 + cr) * R + r0 + rc;
  uint4 o0 = {pk[0], pk[1], pk[2], pk[3]};
  uint4 o1 = {pk[4], pk[5], pk[6], pk[7]};
  *(uint4*)dp       = o0;
  *(uint4*)(dp + 8) = o1;
}

// bf16 V transpose: vt[((b*NKV+g)*HDIM + d)*SEQ + s] = qkv[.. v region ..]
__device__ __forceinline__ void tv_body(const u16* __restrict__ qkv,
                                        u16* __restrict__ vt,
                                        int sx, int dy, int bg, int t,
                                        u16 (*tile)[80]) {
  int s0 = sx * 64;
  int d0 = dy * 64;
  int b = bg >> 2, g = bg & 3;
  int sr = t >> 2, dc = (t & 3) * 16;
  const u16* sp = qkv + (size_t)(b * SEQ + s0 + sr) * QKVW + 4608 + g * HDIM + d0 + dc;
  *(uint4*)&tile[sr][dc]     = *(const uint4*)sp;
  *(uint4*)&tile[sr][dc + 8] = *(const uint4*)(sp + 8);
  __syncthreads();
  int dr = t >> 2, sc = (t & 3) * 16;
  u32 pk[8];
#pragma unroll
  for (int i = 0; i < 8; i++) {
    u32 lo = tile[sc + 2 * i][dr];
    u32 hi = tile[sc + 2 * i + 1][dr];
    pk[i] = lo | (hi << 16);
  }
  u16* dp = vt + ((size_t)bg * HDIM + d0 + dr) * SEQ + s0 + sc;
  uint4 o0 = {pk[0], pk[1], pk[2], pk[3]};
  uint4 o1 = {pk[4], pk[5], pk[6], pk[7]};
  *(uint4*)dp       = o0;
  *(uint4*)(dp + 8) = o1;
}

// RMS-norm (+1+w) + RoPE for one (token, head-row) per wave
__device__ __forceinline__ void nr_body(u16* __restrict__ qkv,
                                        const float* __restrict__ cosb,
                                        const float* __restrict__ sinb,
                                        const float* __restrict__ qw,
                                        const float* __restrict__ kw,
                                        u16* __restrict__ kf,
                                        int blk, int tidx) {
  int wave = tidx >> 6, lane = tidx & 63;
  int tw = blk * 4 + wave;
  int token = tw / 20, r = tw % 20;
  const u16* src;
  u16* dst;
  const float* wptr;
  if (r < 16) {
    src  = qkv + (size_t)token * QKVW + r * 256;       // q of head r
    dst  = (u16*)src;                                  // in place
    wptr = qw;
  } else {
    src  = qkv + (size_t)token * QKVW + 4096 + (r - 16) * HDIM;
    int b = token >> 11, s = token & (SEQ - 1);
    dst  = kf + ((size_t)(b * NKV + (r - 16)) * SEQ + s) * HDIM;
    wptr = kw;
  }
  int d0 = lane * 2;
  u32 x = *(const u32*)(src + d0);
  float x0 = bf2f((u16)(x & 0xffff)), x1 = bf2f((u16)(x >> 16));
  float ss = x0 * x0 + x1 * x1;
#pragma unroll
  for (int off = 1; off < 64; off <<= 1) ss += __shfl_xor(ss, off, 64);
  float sc = rsqrtf(ss * (1.f / 128.f) + 1e-6f);
  float y0 = bf2f(f2bf(x0 * sc * (1.f + wptr[d0])));
  float y1 = bf2f(f2bf(x1 * sc * (1.f + wptr[d0 + 1])));
  float p0 = __shfl_xor(y0, 8, 64);
  float p1 = __shfl_xor(y1, 8, 64);
  float z0 = y0, z1 = y1;
  if (lane < 16) {
    float c0 = cosb[(size_t)token * 32 + d0];
    float c1 = cosb[(size_t)token * 32 + d0 + 1];
    float s0 = sinb[(size_t)token * 32 + d0];
    float s1 = sinb[(size_t)token * 32 + d0 + 1];
    if (lane < 8) { z0 = y0 * c0 - p0 * s0; z1 = y1 * c1 - p1 * s1; }
    else          { z0 = y0 * c0 + p0 * s0; z1 = y1 * c1 + p1 * s1; }
  }
  u32 outp = (u32)f2bf(z0) | ((u32)f2bf(z1) << 16);
  *(u32*)(dst + d0) = outp;
}

// ---------------------------------------------------------------------------
// prep0: conv (8192) | tw wq (2048) | tw wk (256) | tw wv (256) = 10752 blocks
__global__ __launch_bounds__(256) void prep0(const float* __restrict__ hidden,
                                             u16* __restrict__ hidden_bf,
                                             const float* __restrict__ wq,
                                             const float* __restrict__ wk,
                                             const float* __restrict__ wv,
                                             u16* __restrict__ bt_qkv) {
  __shared__ u16 tile[64][80];
  int b = blockIdx.x, t = threadIdx.x;
  if (b < 8192) {
    conv_body(hidden, hidden_bf, b, t);
  } else if (b < 10240) {
    int idx = b - 8192;
    tw_body(wq, bt_qkv, 2048, 4096, idx & 63, idx >> 6, t, tile);
  } else if (b < 10496) {
    int idx = b - 10240;
    tw_body(wk, bt_qkv + (size_t)4096 * 2048, 2048, 512, idx & 7, idx >> 3, t, tile);
  } else {
    int idx = b - 10496;
    tw_body(wv, bt_qkv + (size_t)4608 * 2048, 2048, 512, idx & 7, idx >> 3, t, tile);
  }
}

// ---------------------------------------------------------------------------
// prep1 (post-QKV-gemm): norm_rope (40960) | tv (1024) | tw wo (1024) = 43008
__global__ __launch_bounds__(256) void prep1(u16* __restrict__ qkv,
                                             const float* __restrict__ cosb,
                                             const float* __restrict__ sinb,
                                             const float* __restrict__ qw,
                                             const float* __restrict__ kw,
                                             u16* __restrict__ kf,
                                             u16* __restrict__ vt,
                                             const float* __restrict__ wo,
                                             u16* __restrict__ bt_wo) {
  __shared__ u16 tile[64][80];
  int b = blockIdx.x, t = threadIdx.x;
  if (b < 40960) {
    nr_body(qkv, cosb, sinb, qw, kw, kf, b, t);
  } else if (b < 41984) {
    int idx = b - 40960;
    tv_body(qkv, vt, idx & 31, (idx >> 5) & 1, idx >> 6, t, tile);
  } else {
    int idx = b - 41984;
    tw_body(wo, bt_wo, 2048, 2048, idx & 31, idx >> 5, t, tile);
  }
}

// ---------------------------------------------------------------------------
// GEMM: C[M,N] = A[M,K] * Bt[N,K]^T, bf16 in, fp32 accum.
// 256x256 tile, 8 waves (2x4 of 128x64), MFMA 16x16x32_bf16, BK=32.
// 2-BUFFER ring, 64KB LDS -> 2 BLOCKS/CU (was 3-ring 96KB = 1 block/CU,
// occupancy 18%, MfmaUtil 37%: every barrier stalled the whole CU). With a
// co-resident block, one block computes while the other sits at its
// barrier (m114 wave-level overlap). Stage(t+1) still issues BEFORE
// compute(t) -> one full compute phase of latency hiding (sufficient for
// L2/L3-resident inputs per R8's 4-ring null result); the only loss vs
// 3-ring is waiting vmcnt(0) instead of vmcnt(4), now hidden cross-block.
// __launch_bounds__(512,4) pins 4 waves/SIMD (VGPR<=128; measured 88).
template <bool OUT_F32>
__global__ __launch_bounds__(512, 4) void gemm_bt(const u16* __restrict__ A,
                                                  const u16* __restrict__ Bt,
                                                  void* __restrict__ Cp,
                                                  int M, int N, int K) {
  __shared__ u16 As[2][256 * 32];
  __shared__ u16 Bs[2][256 * 32];
  int tid  = threadIdx.x;
  int lane = tid & 63, wave = tid >> 6;
  int wr = wave >> 2, wc = wave & 3;          // 2 x 4 wave grid
  int col = lane & 15, quad = lane >> 4;
  // XCD-aware block swizzle (bijective: nwg % 8 == 0)
  int nwg = gridDim.x;
  int cpx = nwg >> 3;
  int id  = blockIdx.x;
  int idp = (id & 7) * cpx + (id >> 3);
  int ntile = N >> 8;
  int m0 = (idp / ntile) << 8;
  int n0 = (idp % ntile) << 8;

  v4f acc[8][4];
#pragma unroll
  for (int mi = 0; mi < 8; mi++)
#pragma unroll
    for (int ni = 0; ni < 4; ni++) acc[mi][ni] = (v4f){0.f, 0.f, 0.f, 0.f};

  int srow = tid >> 2;            // 0..127
  int skc  = (tid & 3) * 8;       // 0,8,16,24
  const u16* ag = A  + (size_t)(m0 + srow) * K + skc;
  const u16* bg = Bt + (size_t)(n0 + srow) * K + skc;
  const size_t rowK128 = (size_t)128 * K;

#define STAGE(buf, k0)                                        \
  do {                                                        \
    gld_lds16(ag + (k0),           &As[buf][tid * 8]);        \
    gld_lds16(ag + rowK128 + (k0), &As[buf][4096 + tid * 8]); \
    gld_lds16(bg + (k0),           &Bs[buf][tid * 8]);        \
    gld_lds16(bg + rowK128 + (k0), &Bs[buf][4096 + tid * 8]); \
  } while (0)

  STAGE(0, 0);
  asm volatile("s_waitcnt vmcnt(0)\n\ts_barrier" ::: "memory");

  const int NT = K >> 5;
  for (int t = 0; t < NT; ++t) {
    int cb = t & 1;
    if (t + 1 < NT) STAGE(cb ^ 1, (t + 1) << 5);   // in flight during compute
    v8bf bfr[4];
#pragma unroll
    for (int ni = 0; ni < 4; ni++)
      bfr[ni] = *(const v8bf*)&Bs[cb][(wc * 64 + ni * 16 + col) * 32 + quad * 8];
    __builtin_amdgcn_s_setprio(1);
#pragma unroll
    for (int mi = 0; mi < 8; mi++) {
      v8bf a = *(const v8bf*)&As[cb][(wr * 128 + mi * 16 + col) * 32 + quad * 8];
#pragma unroll
      for (int ni = 0; ni < 4; ni++)
        acc[mi][ni] = __builtin_amdgcn_mfma_f32_16x16x32_bf16(a, bfr[ni], acc[mi][ni], 0, 0, 0);
    }
    __builtin_amdgcn_s_setprio(0);
    // next tile landed (own loads) + all waves done reading buf cb
    asm volatile("s_waitcnt vmcnt(0)\n\ts_barrier" ::: "memory");
  }
#undef STAGE

#pragma unroll
  for (int mi = 0; mi < 8; mi++)
#pragma unroll
    for (int ni = 0; ni < 4; ni++) {
      int r_ = m0 + wr * 128 + mi * 16 + quad * 4;
      int c_ = n0 + wc * 64 + ni * 16 + col;
#pragma unroll
      for (int r = 0; r < 4; r++) {
        if (OUT_F32) ((float*)Cp)[(size_t)(r_ + r) * N + c_] = acc[mi][ni][r];
        else         ((u16*)Cp)[(size_t)(r_ + r) * N + c_]   = f2bf(acc[mi][ni][r]);
      }
    }
}

// ---------------------------------------------------------------------------
// Causal GQA flash attention + sigmoid-gate epilogue (R11 kernel, kept).
// Paired q-tiles {bx, 15-bx}: uniform 34 k-tiles/block, 512 blocks.
// grid (8, NHEAD, NB), block 512.
__global__ __launch_bounds__(512) void attn_kernel(const u16* __restrict__ qkv,
                                                   const u16* __restrict__ kf,
                                                   const u16* __restrict__ vt,
                                                   u16* __restrict__ ga) {
  __shared__ u16 ks[64 * 136];      // K-tile [key][d], stride 136
  __shared__ u16 vs[128 * 88];      // V-tile [d][sigma(key)], stride 88
  int tid = threadIdx.x, lane = tid & 63, wave = tid >> 6;   // wave 0..7
  int col = lane & 15, quad = lane >> 4;
  int h = blockIdx.y, b = blockIdx.z;
  int g = h >> 2;
  const float scl2 = 0.08838834764831845f * 1.4426950408889634f;  // D^-.5 * log2e

  const u16* kfb = kf + (size_t)(b * NKV + g) * SEQ * HDIM;
  const u16* vtb = vt + (size_t)(b * NKV + g) * HDIM * SEQ;

  // staging maps, 512 threads, 2 passes each
  int ksr = tid >> 4, ksd = (tid & 15) * 8;   // K: rows p*32+ksr (0..63)
  int vsd = tid >> 3, w8 = tid & 7;           // V: d = p*64+vsd (0..127)
  // sigma(s)=(s5,s3,s2,s4,s1,s0); src s = 8*w8 + i, w8 bits = (s5,s4,s3)
  int voff = 32 * ((w8 >> 2) & 1) + 16 * (w8 & 1) + 4 * ((w8 >> 1) & 1);
  int vsrc = w8 * 8;

#pragma unroll
  for (int qsel = 0; qsel < 2; ++qsel) {
    int qt = qsel ? 15 - blockIdx.x : blockIdx.x;
    int qw0 = qt * 128 + wave * 16;
    int myq = qw0 + col;            // this lane's query row

    // Q fragments (B-layout: n=query=lane&15, k=quad*8+j)
    v8bf qfr[4];
    const u16* qbase = qkv + (size_t)(b * SEQ + myq) * QKVW + h * 256 + quad * 8;
#pragma unroll
    for (int kc = 0; kc < 4; kc++) qfr[kc] = *(const v8bf*)(qbase + kc * 32);

    v4f o[8];                       // O^T: o[dt][r] = O[d=16dt+4*quad+r][myq]
#pragma unroll
    for (int nt = 0; nt < 8; nt++) o[nt] = (v4f){0.f, 0.f, 0.f, 0.f};
    float l = 0.f;                  // per-quad partial row-sum
    float m = -1e30f;               // running max

    int nk = 2 * qt + 2;            // K/V tiles of 64 covering keys <= qt*128+127
    for (int it = 0; it < nk; it++) {
      int k0 = it * 64;
      __syncthreads();  // previous iteration's LDS reads complete
#pragma unroll
      for (int p = 0; p < 2; p++)
        *(uint4*)&ks[(p * 32 + ksr) * 136 + ksd] =
            *(const uint4*)&kfb[(size_t)(k0 + p * 32 + ksr) * HDIM + ksd];
#pragma unroll
      for (int p = 0; p < 2; p++) {
        int d = p * 64 + vsd;
        uint4 gv = *(const uint4*)&vtb[(size_t)d * SEQ + k0 + vsrc];
        uint2 w0 = {gv.x, gv.y};
        uint2 w1 = {gv.z, gv.w};
        *(uint2*)&vs[d * 88 + voff]     = w0;   // keys i=0..3 -> voff..voff+3
        *(uint2*)&vs[d * 88 + voff + 8] = w1;   // keys i=4..7 -> voff+8..
      }
      __syncthreads();

      // --- S^T = K Q^T: st[t][r] = S[key=k0+16t+4*quad+r][myq] ---
      v4f st[4];
      __builtin_amdgcn_s_setprio(1);
#pragma unroll
      for (int t = 0; t < 4; t++) {
        v4f acc = (v4f){0.f, 0.f, 0.f, 0.f};
#pragma unroll
        for (int kc = 0; kc < 4; kc++) {
          v8bf kfr = *(const v8bf*)&ks[(t * 16 + col) * 136 + kc * 32 + quad * 8];
          acc = __builtin_amdgcn_mfma_f32_16x16x32_bf16(kfr, qfr[kc], acc, 0, 0, 0);
        }
        st[t] = acc;
      }
      __builtin_amdgcn_s_setprio(0);

      // --- in-register online softmax (exp2 domain) ---
      bool maskw = (k0 + 63 > qw0); // wave-uniform: any key can exceed a row
      float pmax = -1e30f;
#pragma unroll
      for (int t = 0; t < 4; t++)
#pragma unroll
        for (int r = 0; r < 4; r++) {
          float x = st[t][r] * scl2;
          if (maskw && (k0 + t * 16 + quad * 4 + r > myq)) x = -1e30f;
          st[t][r] = x;
          pmax = fmaxf(pmax, x);
        }
      pmax = fmaxf(pmax, __shfl_xor(pmax, 16, 64));
      pmax = fmaxf(pmax, __shfl_xor(pmax, 32, 64));
      if (__any(pmax > m + 8.f)) {       // defer-max: rescale only on growth
        float nm = fmaxf(m, pmax);
        float al = exp2f(m - nm);
        m = nm;
#pragma unroll
        for (int nt = 0; nt < 8; nt++)
#pragma unroll
          for (int r = 0; r < 4; r++) o[nt][r] *= al;
        l *= al;
      }
      // P in bf16, packed directly in PV B-fragment order (lane-local)
      v8bf pb0, pb1;
      float ls = 0.f;
#pragma unroll
      for (int t = 0; t < 4; t++)
#pragma unroll
        for (int r = 0; r < 4; r++) {
          float p = exp2f(st[t][r] - m);
          ls += p;
          if (t < 2) pb0[t * 4 + r] = (__bf16)p;
          else       pb1[(t - 2) * 4 + r] = (__bf16)p;
        }
      l += ls;

      // --- O^T += V^T P : A=V-frag (m=d), B=P-frag (n=query) ---
      __builtin_amdgcn_s_setprio(1);
#pragma unroll
      for (int nt = 0; nt < 8; nt++) {
        v8bf vb0 = *(const v8bf*)&vs[(nt * 16 + col) * 88 + quad * 8];
        v8bf vb1 = *(const v8bf*)&vs[(nt * 16 + col) * 88 + 32 + quad * 8];
        o[nt] = __builtin_amdgcn_mfma_f32_16x16x32_bf16(vb0, pb0, o[nt], 0, 0, 0);
        o[nt] = __builtin_amdgcn_mfma_f32_16x16x32_bf16(vb1, pb1, o[nt], 0, 0, 0);
      }
      __builtin_amdgcn_s_setprio(0);
    }

    // --- final row-sum across quads, normalize, sigmoid-gate, store ---
    l += __shfl_xor(l, 16, 64);
    l += __shfl_xor(l, 32, 64);
    float inv = 1.f / l;
    const u16* gb = qkv + (size_t)(b * SEQ + myq) * QKVW + h * 256 + 128 + quad * 4;
    u16* ob = ga + (size_t)(b * SEQ + myq) * 2048 + h * HDIM + quad * 4;
#pragma unroll
    for (int nt = 0; nt < 8; nt++) {
      uint2 gw = *(const uint2*)(gb + nt * 16);
      float g0 = bf2f((u16)(gw.x & 0xffff)), g1 = bf2f((u16)(gw.x >> 16));
      float g2 = bf2f((u16)(gw.y & 0xffff)), g3 = bf2f((u16)(gw.y >> 16));
      float a0 = o[nt][0] * inv * (1.f / (1.f + expf(-g0)));
      float a1 = o[nt][1] * inv * (1.f / (1.f + expf(-g1)));
      float a2 = o[nt][2] * inv * (1.f / (1.f + expf(-g2)));
      float a3 = o[nt][3] * inv * (1.f / (1.f + expf(-g3)));
      uint2 ow;
      ow.x = (u32)f2bf(a0) | ((u32)f2bf(a1) << 16);
      ow.y = (u32)f2bf(a2) | ((u32)f2bf(a3) << 16);
      *(uint2*)(ob + nt * 16) = ow;
    }
  }
}

// ---------------------------------------------------------------------------
extern "C" void kernel_launch(void* const* d_in, const int* in_sizes, int n_in,
                              void* d_out, int out_size, void* d_ws, size_t ws_size,
                              hipStream_t stream) {
  const float* hidden = (const float*)d_in[0];
  const float* cosb   = (const float*)d_in[1];
  const float* sinb   = (const float*)d_in[2];
  // d_in[3] attention_mask: exact causal triu(-1e9) -> applied analytically
  const float* wq  = (const float*)d_in[4];
  const float* wk  = (const float*)d_in[5];
  const float* wv  = (const float*)d_in[6];
  const float* wo  = (const float*)d_in[7];
  const float* qnw = (const float*)d_in[8];
  const float* knw = (const float*)d_in[9];
  float* out = (float*)d_out;

  u16* ws      = (u16*)d_ws;
  u16* qkv_raw = ws;
  u16* region2 = qkv_raw + (size_t)8192 * QKVW;
  u16* region3 = region2 + (size_t)8192 * 2048;
  u16* hidden_bf = region2;
  u16* g_attn    = region2;
  u16* bt_qkv    = region3;
  u16* vt        = region3;
  u16* bt_wo     = region3 + (size_t)4194304;
  u16* k_f       = region3 + (size_t)8388608;

  // 1) fused: hidden fp32->bf16 + wq/wk/wv convert-transposes
  prep0<<<dim3(10752), 256, 0, stream>>>(hidden, hidden_bf, wq, wk, wv, bt_qkv);
  // 2) fused QKV projection (bf16 out)
  gemm_bt<false><<<dim3(640), 512, 0, stream>>>(hidden_bf, bt_qkv, qkv_raw, 8192, QKVW, 2048);
  // 3) fused: norm_rope + V-transpose + wo convert-transpose
  prep1<<<dim3(43008), 256, 0, stream>>>(qkv_raw, cosb, sinb, qnw, knw, k_f, vt, wo, bt_wo);
  // 4) causal flash attention + gating (paired q-tiles, uniform work)
  attn_kernel<<<dim3(8, NHEAD, NB), 512, 0, stream>>>(qkv_raw, k_f, vt, g_attn);
  // 5) output projection, fp32 store
  gemm_bt<true><<<dim3(256), 512, 0, stream>>>(g_attn, bt_wo, out, 8192, 2048, 2048);
}

// Round 13
// 614.712 us; speedup vs baseline: 3.3101x; 3.3101x over previous
//
#include <hip/hip_runtime.h>

// Problem constants
#define SEQ   2048
#define NHEAD 16
#define NKV   4
#define HDIM  128
#define NB    4
// qkv_raw row layout: [qg 0..4095 | k 4096..4607 | v 4608..5119]
#define QKVW  5120

typedef unsigned short u16;
typedef unsigned int   u32;
typedef __bf16 v8bf __attribute__((ext_vector_type(8)));
typedef float  v4f  __attribute__((ext_vector_type(4)));

__device__ __forceinline__ u16 f2bf(float f) {
  u32 u = __float_as_uint(f);
  u += 0x7fffu + ((u >> 16) & 1u);
  return (u16)(u >> 16);
}
__device__ __forceinline__ float bf2f(u16 b) {
  return __uint_as_float(((u32)b) << 16);
}

// Async global->LDS DMA, 16B per lane. LDS dest must be linear in lane order
// (wave-uniform base + lane*16).
__device__ __forceinline__ void gld_lds16(const u16* g, u16* l) {
  __builtin_amdgcn_global_load_lds(
      (const __attribute__((address_space(1))) u32*)(unsigned long long)(uintptr_t)g,
      (__attribute__((address_space(3))) u32*)(u32)(uintptr_t)l,
      16, 0, 0);
}

// ---------------------------------------------------------------------------
// Device bodies for the fused prep kernels
// ---------------------------------------------------------------------------
__device__ __forceinline__ void conv_body(const float* __restrict__ s,
                                          u16* __restrict__ d, int blk, int t) {
  size_t i = ((size_t)blk * 256 + t) * 8;
  float4 a = *(const float4*)(s + i);
  float4 b = *(const float4*)(s + i + 4);
  uint4 o;
  o.x = (u32)f2bf(a.x) | ((u32)f2bf(a.y) << 16);
  o.y = (u32)f2bf(a.z) | ((u32)f2bf(a.w) << 16);
  o.z = (u32)f2bf(b.x) | ((u32)f2bf(b.y) << 16);
  o.w = (u32)f2bf(b.z) | ((u32)f2bf(b.w) << 16);
  *(uint4*)(d + i) = o;
}

// fp32 src -> bf16 transposed dst: dst[c*R + r] = bf16(src[r*C + c])
__device__ __forceinline__ void tw_body(const float* __restrict__ src,
                                        u16* __restrict__ dst, int R, int C,
                                        int bx, int by, int t,
                                        u16 (*tile)[80]) {
  int r0 = by * 64, c0 = bx * 64;
  int rr = t >> 2, cc = (t & 3) * 16;
  const float* sp = src + (size_t)(r0 + rr) * C + c0 + cc;
  float4 f0 = *(const float4*)sp;
  float4 f1 = *(const float4*)(sp + 4);
  float4 f2 = *(const float4*)(sp + 8);
  float4 f3 = *(const float4*)(sp + 12);
  u16* tp = &tile[rr][cc];
  tp[0] = f2bf(f0.x);  tp[1] = f2bf(f0.y);  tp[2] = f2bf(f0.z);  tp[3] = f2bf(f0.w);
  tp[4] = f2bf(f1.x);  tp[5] = f2bf(f1.y);  tp[6] = f2bf(f1.z);  tp[7] = f2bf(f1.w);
  tp[8] = f2bf(f2.x);  tp[9] = f2bf(f2.y);  tp[10] = f2bf(f2.z); tp[11] = f2bf(f2.w);
  tp[12] = f2bf(f3.x); tp[13] = f2bf(f3.y); tp[14] = f2bf(f3.z); tp[15] = f2bf(f3.w);
  __syncthreads();
  int cr = t >> 2, rc = (t & 3) * 16;
  u32 pk[8];
#pragma unroll
  for (int i = 0; i < 8; i++) {
    u32 lo = tile[rc + 2 * i][cr];
    u32 hi = tile[rc + 2 * i + 1][cr];
    pk[i] = lo | (hi << 16);
  }
  u16* dp = dst + (size_t)(c0 + cr) * R + r0 + rc;
  uint4 o0 = {pk[0], pk[1], pk[2], pk[3]};
  uint4 o1 = {pk[4], pk[5], pk[6], pk[7]};
  *(uint4*)dp       = o0;
  *(uint4*)(dp + 8) = o1;
}

// bf16 V transpose: vt[((b*NKV+g)*HDIM + d)*SEQ + s] = qkv[.. v region ..]
__device__ __forceinline__ void tv_body(const u16* __restrict__ qkv,
                                        u16* __restrict__ vt,
                                        int sx, int dy, int bg, int t,
                                        u16 (*tile)[80]) {
  int s0 = sx * 64;
  int d0 = dy * 64;
  int b = bg >> 2, g = bg & 3;
  int sr = t >> 2, dc = (t & 3) * 16;
  const u16* sp = qkv + (size_t)(b * SEQ + s0 + sr) * QKVW + 4608 + g * HDIM + d0 + dc;
  *(uint4*)&tile[sr][dc]     = *(const uint4*)sp;
  *(uint4*)&tile[sr][dc + 8] = *(const uint4*)(sp + 8);
  __syncthreads();
  int dr = t >> 2, sc = (t & 3) * 16;
  u32 pk[8];
#pragma unroll
  for (int i = 0; i < 8; i++) {
    u32 lo = tile[sc + 2 * i][dr];
    u32 hi = tile[sc + 2 * i + 1][dr];
    pk[i] = lo | (hi << 16);
  }
  u16* dp = vt + ((size_t)bg * HDIM + d0 + dr) * SEQ + s0 + sc;
  uint4 o0 = {pk[0], pk[1], pk[2], pk[3]};
  uint4 o1 = {pk[4], pk[5], pk[6], pk[7]};
  *(uint4*)dp       = o0;
  *(uint4*)(dp + 8) = o1;
}

// RMS-norm (+1+w) + RoPE for one (token, head-row) per wave
__device__ __forceinline__ void nr_body(u16* __restrict__ qkv,
                                        const float* __restrict__ cosb,
                                        const float* __restrict__ sinb,
                                        const float* __restrict__ qw,
                                        const float* __restrict__ kw,
                                        u16* __restrict__ kf,
                                        int blk, int tidx) {
  int wave = tidx >> 6, lane = tidx & 63;
  int tw = blk * 4 + wave;
  int token = tw / 20, r = tw % 20;
  const u16* src;
  u16* dst;
  const float* wptr;
  if (r < 16) {
    src  = qkv + (size_t)token * QKVW + r * 256;       // q of head r
    dst  = (u16*)src;                                  // in place
    wptr = qw;
  } else {
    src  = qkv + (size_t)token * QKVW + 4096 + (r - 16) * HDIM;
    int b = token >> 11, s = token & (SEQ - 1);
    dst  = kf + ((size_t)(b * NKV + (r - 16)) * SEQ + s) * HDIM;
    wptr = kw;
  }
  int d0 = lane * 2;
  u32 x = *(const u32*)(src + d0);
  float x0 = bf2f((u16)(x & 0xffff)), x1 = bf2f((u16)(x >> 16));
  float ss = x0 * x0 + x1 * x1;
#pragma unroll
  for (int off = 1; off < 64; off <<= 1) ss += __shfl_xor(ss, off, 64);
  float sc = rsqrtf(ss * (1.f / 128.f) + 1e-6f);
  float y0 = bf2f(f2bf(x0 * sc * (1.f + wptr[d0])));
  float y1 = bf2f(f2bf(x1 * sc * (1.f + wptr[d0 + 1])));
  float p0 = __shfl_xor(y0, 8, 64);
  float p1 = __shfl_xor(y1, 8, 64);
  float z0 = y0, z1 = y1;
  if (lane < 16) {
    float c0 = cosb[(size_t)token * 32 + d0];
    float c1 = cosb[(size_t)token * 32 + d0 + 1];
    float s0 = sinb[(size_t)token * 32 + d0];
    float s1 = sinb[(size_t)token * 32 + d0 + 1];
    if (lane < 8) { z0 = y0 * c0 - p0 * s0; z1 = y1 * c1 - p1 * s1; }
    else          { z0 = y0 * c0 + p0 * s0; z1 = y1 * c1 + p1 * s1; }
  }
  u32 outp = (u32)f2bf(z0) | ((u32)f2bf(z1) << 16);
  *(u32*)(dst + d0) = outp;
}

// ---------------------------------------------------------------------------
// prep0: conv (8192) | tw wq (2048) | tw wk (256) | tw wv (256) = 10752 blocks
__global__ __launch_bounds__(256) void prep0(const float* __restrict__ hidden,
                                             u16* __restrict__ hidden_bf,
                                             const float* __restrict__ wq,
                                             const float* __restrict__ wk,
                                             const float* __restrict__ wv,
                                             u16* __restrict__ bt_qkv) {
  __shared__ u16 tile[64][80];
  int b = blockIdx.x, t = threadIdx.x;
  if (b < 8192) {
    conv_body(hidden, hidden_bf, b, t);
  } else if (b < 10240) {
    int idx = b - 8192;
    tw_body(wq, bt_qkv, 2048, 4096, idx & 63, idx >> 6, t, tile);
  } else if (b < 10496) {
    int idx = b - 10240;
    tw_body(wk, bt_qkv + (size_t)4096 * 2048, 2048, 512, idx & 7, idx >> 3, t, tile);
  } else {
    int idx = b - 10496;
    tw_body(wv, bt_qkv + (size_t)4608 * 2048, 2048, 512, idx & 7, idx >> 3, t, tile);
  }
}

// ---------------------------------------------------------------------------
// prep1 (post-QKV-gemm): norm_rope (40960) | tv (1024) | tw wo (1024) = 43008
__global__ __launch_bounds__(256) void prep1(u16* __restrict__ qkv,
                                             const float* __restrict__ cosb,
                                             const float* __restrict__ sinb,
                                             const float* __restrict__ qw,
                                             const float* __restrict__ kw,
                                             u16* __restrict__ kf,
                                             u16* __restrict__ vt,
                                             const float* __restrict__ wo,
                                             u16* __restrict__ bt_wo) {
  __shared__ u16 tile[64][80];
  int b = blockIdx.x, t = threadIdx.x;
  if (b < 40960) {
    nr_body(qkv, cosb, sinb, qw, kw, kf, b, t);
  } else if (b < 41984) {
    int idx = b - 40960;
    tv_body(qkv, vt, idx & 31, (idx >> 5) & 1, idx >> 6, t, tile);
  } else {
    int idx = b - 41984;
    tw_body(wo, bt_wo, 2048, 2048, idx & 31, idx >> 5, t, tile);
  }
}

// ---------------------------------------------------------------------------
// GEMM: C[M,N] = A[M,K] * Bt[N,K]^T, bf16 in, fp32 accum.
// 256x256 tile, 8 waves (2x4 of 128x64), MFMA 16x16x32_bf16, BK=32.
// 2-BUFFER ring, 64KB LDS -> 2 blocks/CU via LDS; __launch_bounds__(512,2)
// (R12's (512,4) forced a 128-VGPR cap -> acc spilled to scratch: 2.6GB
// writes/dispatch, MfmaUtil 5%. bound=2 restores VGPR 88, no spill; 88<=128
// means HW can still co-schedule 4 waves/SIMD = 2 blocks/CU on LDS grounds.)
// Stage(t+1) issues BEFORE compute(t); vmcnt(0)+barrier per K-step; the
// drain stall is hidden by the co-resident block (m114 overlap).
template <bool OUT_F32>
__global__ __launch_bounds__(512, 2) void gemm_bt(const u16* __restrict__ A,
                                                  const u16* __restrict__ Bt,
                                                  void* __restrict__ Cp,
                                                  int M, int N, int K) {
  __shared__ u16 As[2][256 * 32];
  __shared__ u16 Bs[2][256 * 32];
  int tid  = threadIdx.x;
  int lane = tid & 63, wave = tid >> 6;
  int wr = wave >> 2, wc = wave & 3;          // 2 x 4 wave grid
  int col = lane & 15, quad = lane >> 4;
  // XCD-aware block swizzle (bijective: nwg % 8 == 0)
  int nwg = gridDim.x;
  int cpx = nwg >> 3;
  int id  = blockIdx.x;
  int idp = (id & 7) * cpx + (id >> 3);
  int ntile = N >> 8;
  int m0 = (idp / ntile) << 8;
  int n0 = (idp % ntile) << 8;

  v4f acc[8][4];
#pragma unroll
  for (int mi = 0; mi < 8; mi++)
#pragma unroll
    for (int ni = 0; ni < 4; ni++) acc[mi][ni] = (v4f){0.f, 0.f, 0.f, 0.f};

  int srow = tid >> 2;            // 0..127
  int skc  = (tid & 3) * 8;       // 0,8,16,24
  const u16* ag = A  + (size_t)(m0 + srow) * K + skc;
  const u16* bg = Bt + (size_t)(n0 + srow) * K + skc;
  const size_t rowK128 = (size_t)128 * K;

#define STAGE(buf, k0)                                        \
  do {                                                        \
    gld_lds16(ag + (k0),           &As[buf][tid * 8]);        \
    gld_lds16(ag + rowK128 + (k0), &As[buf][4096 + tid * 8]); \
    gld_lds16(bg + (k0),           &Bs[buf][tid * 8]);        \
    gld_lds16(bg + rowK128 + (k0), &Bs[buf][4096 + tid * 8]); \
  } while (0)

  STAGE(0, 0);
  asm volatile("s_waitcnt vmcnt(0)\n\ts_barrier" ::: "memory");

  const int NT = K >> 5;
  for (int t = 0; t < NT; ++t) {
    int cb = t & 1;
    if (t + 1 < NT) STAGE(cb ^ 1, (t + 1) << 5);   // in flight during compute
    v8bf bfr[4];
#pragma unroll
    for (int ni = 0; ni < 4; ni++)
      bfr[ni] = *(const v8bf*)&Bs[cb][(wc * 64 + ni * 16 + col) * 32 + quad * 8];
    __builtin_amdgcn_s_setprio(1);
#pragma unroll
    for (int mi = 0; mi < 8; mi++) {
      v8bf a = *(const v8bf*)&As[cb][(wr * 128 + mi * 16 + col) * 32 + quad * 8];
#pragma unroll
      for (int ni = 0; ni < 4; ni++)
        acc[mi][ni] = __builtin_amdgcn_mfma_f32_16x16x32_bf16(a, bfr[ni], acc[mi][ni], 0, 0, 0);
    }
    __builtin_amdgcn_s_setprio(0);
    // next tile landed (own loads) + all waves done reading buf cb
    asm volatile("s_waitcnt vmcnt(0)\n\ts_barrier" ::: "memory");
  }
#undef STAGE

#pragma unroll
  for (int mi = 0; mi < 8; mi++)
#pragma unroll
    for (int ni = 0; ni < 4; ni++) {
      int r_ = m0 + wr * 128 + mi * 16 + quad * 4;
      int c_ = n0 + wc * 64 + ni * 16 + col;
#pragma unroll
      for (int r = 0; r < 4; r++) {
        if (OUT_F32) ((float*)Cp)[(size_t)(r_ + r) * N + c_] = acc[mi][ni][r];
        else         ((u16*)Cp)[(size_t)(r_ + r) * N + c_]   = f2bf(acc[mi][ni][r]);
      }
    }
}

// ---------------------------------------------------------------------------
// Causal GQA flash attention + sigmoid-gate epilogue (R11 kernel, kept).
// Paired q-tiles {bx, 15-bx}: uniform 34 k-tiles/block, 512 blocks.
// grid (8, NHEAD, NB), block 512.
__global__ __launch_bounds__(512) void attn_kernel(const u16* __restrict__ qkv,
                                                   const u16* __restrict__ kf,
                                                   const u16* __restrict__ vt,
                                                   u16* __restrict__ ga) {
  __shared__ u16 ks[64 * 136];      // K-tile [key][d], stride 136
  __shared__ u16 vs[128 * 88];      // V-tile [d][sigma(key)], stride 88
  int tid = threadIdx.x, lane = tid & 63, wave = tid >> 6;   // wave 0..7
  int col = lane & 15, quad = lane >> 4;
  int h = blockIdx.y, b = blockIdx.z;
  int g = h >> 2;
  const float scl2 = 0.08838834764831845f * 1.4426950408889634f;  // D^-.5 * log2e

  const u16* kfb = kf + (size_t)(b * NKV + g) * SEQ * HDIM;
  const u16* vtb = vt + (size_t)(b * NKV + g) * HDIM * SEQ;

  // staging maps, 512 threads, 2 passes each
  int ksr = tid >> 4, ksd = (tid & 15) * 8;   // K: rows p*32+ksr (0..63)
  int vsd = tid >> 3, w8 = tid & 7;           // V: d = p*64+vsd (0..127)
  // sigma(s)=(s5,s3,s2,s4,s1,s0); src s = 8*w8 + i, w8 bits = (s5,s4,s3)
  int voff = 32 * ((w8 >> 2) & 1) + 16 * (w8 & 1) + 4 * ((w8 >> 1) & 1);
  int vsrc = w8 * 8;

#pragma unroll
  for (int qsel = 0; qsel < 2; ++qsel) {
    int qt = qsel ? 15 - blockIdx.x : blockIdx.x;
    int qw0 = qt * 128 + wave * 16;
    int myq = qw0 + col;            // this lane's query row

    // Q fragments (B-layout: n=query=lane&15, k=quad*8+j)
    v8bf qfr[4];
    const u16* qbase = qkv + (size_t)(b * SEQ + myq) * QKVW + h * 256 + quad * 8;
#pragma unroll
    for (int kc = 0; kc < 4; kc++) qfr[kc] = *(const v8bf*)(qbase + kc * 32);

    v4f o[8];                       // O^T: o[dt][r] = O[d=16dt+4*quad+r][myq]
#pragma unroll
    for (int nt = 0; nt < 8; nt++) o[nt] = (v4f){0.f, 0.f, 0.f, 0.f};
    float l = 0.f;                  // per-quad partial row-sum
    float m = -1e30f;               // running max

    int nk = 2 * qt + 2;            // K/V tiles of 64 covering keys <= qt*128+127
    for (int it = 0; it < nk; it++) {
      int k0 = it * 64;
      __syncthreads();  // previous iteration's LDS reads complete
#pragma unroll
      for (int p = 0; p < 2; p++)
        *(uint4*)&ks[(p * 32 + ksr) * 136 + ksd] =
            *(const uint4*)&kfb[(size_t)(k0 + p * 32 + ksr) * HDIM + ksd];
#pragma unroll
      for (int p = 0; p < 2; p++) {
        int d = p * 64 + vsd;
        uint4 gv = *(const uint4*)&vtb[(size_t)d * SEQ + k0 + vsrc];
        uint2 w0 = {gv.x, gv.y};
        uint2 w1 = {gv.z, gv.w};
        *(uint2*)&vs[d * 88 + voff]     = w0;   // keys i=0..3 -> voff..voff+3
        *(uint2*)&vs[d * 88 + voff + 8] = w1;   // keys i=4..7 -> voff+8..
      }
      __syncthreads();

      // --- S^T = K Q^T: st[t][r] = S[key=k0+16t+4*quad+r][myq] ---
      v4f st[4];
      __builtin_amdgcn_s_setprio(1);
#pragma unroll
      for (int t = 0; t < 4; t++) {
        v4f acc = (v4f){0.f, 0.f, 0.f, 0.f};
#pragma unroll
        for (int kc = 0; kc < 4; kc++) {
          v8bf kfr = *(const v8bf*)&ks[(t * 16 + col) * 136 + kc * 32 + quad * 8];
          acc = __builtin_amdgcn_mfma_f32_16x16x32_bf16(kfr, qfr[kc], acc, 0, 0, 0);
        }
        st[t] = acc;
      }
      __builtin_amdgcn_s_setprio(0);

      // --- in-register online softmax (exp2 domain) ---
      bool maskw = (k0 + 63 > qw0); // wave-uniform: any key can exceed a row
      float pmax = -1e30f;
#pragma unroll
      for (int t = 0; t < 4; t++)
#pragma unroll
        for (int r = 0; r < 4; r++) {
          float x = st[t][r] * scl2;
          if (maskw && (k0 + t * 16 + quad * 4 + r > myq)) x = -1e30f;
          st[t][r] = x;
          pmax = fmaxf(pmax, x);
        }
      pmax = fmaxf(pmax, __shfl_xor(pmax, 16, 64));
      pmax = fmaxf(pmax, __shfl_xor(pmax, 32, 64));
      if (__any(pmax > m + 8.f)) {       // defer-max: rescale only on growth
        float nm = fmaxf(m, pmax);
        float al = exp2f(m - nm);
        m = nm;
#pragma unroll
        for (int nt = 0; nt < 8; nt++)
#pragma unroll
          for (int r = 0; r < 4; r++) o[nt][r] *= al;
        l *= al;
      }
      // P in bf16, packed directly in PV B-fragment order (lane-local)
      v8bf pb0, pb1;
      float ls = 0.f;
#pragma unroll
      for (int t = 0; t < 4; t++)
#pragma unroll
        for (int r = 0; r < 4; r++) {
          float p = exp2f(st[t][r] - m);
          ls += p;
          if (t < 2) pb0[t * 4 + r] = (__bf16)p;
          else       pb1[(t - 2) * 4 + r] = (__bf16)p;
        }
      l += ls;

      // --- O^T += V^T P : A=V-frag (m=d), B=P-frag (n=query) ---
      __builtin_amdgcn_s_setprio(1);
#pragma unroll
      for (int nt = 0; nt < 8; nt++) {
        v8bf vb0 = *(const v8bf*)&vs[(nt * 16 + col) * 88 + quad * 8];
        v8bf vb1 = *(const v8bf*)&vs[(nt * 16 + col) * 88 + 32 + quad * 8];
        o[nt] = __builtin_amdgcn_mfma_f32_16x16x32_bf16(vb0, pb0, o[nt], 0, 0, 0);
        o[nt] = __builtin_amdgcn_mfma_f32_16x16x32_bf16(vb1, pb1, o[nt], 0, 0, 0);
      }
      __builtin_amdgcn_s_setprio(0);
    }

    // --- final row-sum across quads, normalize, sigmoid-gate, store ---
    l += __shfl_xor(l, 16, 64);
    l += __shfl_xor(l, 32, 64);
    float inv = 1.f / l;
    const u16* gb = qkv + (size_t)(b * SEQ + myq) * QKVW + h * 256 + 128 + quad * 4;
    u16* ob = ga + (size_t)(b * SEQ + myq) * 2048 + h * HDIM + quad * 4;
#pragma unroll
    for (int nt = 0; nt < 8; nt++) {
      uint2 gw = *(const uint2*)(gb + nt * 16);
      float g0 = bf2f((u16)(gw.x & 0xffff)), g1 = bf2f((u16)(gw.x >> 16));
      float g2 = bf2f((u16)(gw.y & 0xffff)), g3 = bf2f((u16)(gw.y >> 16));
      float a0 = o[nt][0] * inv * (1.f / (1.f + expf(-g0)));
      float a1 = o[nt][1] * inv * (1.f / (1.f + expf(-g1)));
      float a2 = o[nt][2] * inv * (1.f / (1.f + expf(-g2)));
      float a3 = o[nt][3] * inv * (1.f / (1.f + expf(-g3)));
      uint2 ow;
      ow.x = (u32)f2bf(a0) | ((u32)f2bf(a1) << 16);
      ow.y = (u32)f2bf(a2) | ((u32)f2bf(a3) << 16);
      *(uint2*)(ob + nt * 16) = ow;
    }
  }
}

// ---------------------------------------------------------------------------
extern "C" void kernel_launch(void* const* d_in, const int* in_sizes, int n_in,
                              void* d_out, int out_size, void* d_ws, size_t ws_size,
                              hipStream_t stream) {
  const float* hidden = (const float*)d_in[0];
  const float* cosb   = (const float*)d_in[1];
  const float* sinb   = (const float*)d_in[2];
  // d_in[3] attention_mask: exact causal triu(-1e9) -> applied analytically
  const float* wq  = (const float*)d_in[4];
  const float* wk  = (const float*)d_in[5];
  const float* wv  = (const float*)d_in[6];
  const float* wo  = (const float*)d_in[7];
  const float* qnw = (const float*)d_in[8];
  const float* knw = (const float*)d_in[9];
  float* out = (float*)d_out;

  u16* ws      = (u16*)d_ws;
  u16* qkv_raw = ws;
  u16* region2 = qkv_raw + (size_t)8192 * QKVW;
  u16* region3 = region2 + (size_t)8192 * 2048;
  u16* hidden_bf = region2;
  u16* g_attn    = region2;
  u16* bt_qkv    = region3;
  u16* vt        = region3;
  u16* bt_wo     = region3 + (size_t)4194304;
  u16* k_f       = region3 + (size_t)8388608;

  // 1) fused: hidden fp32->bf16 + wq/wk/wv convert-transposes
  prep0<<<dim3(10752), 256, 0, stream>>>(hidden, hidden_bf, wq, wk, wv, bt_qkv);
  // 2) fused QKV projection (bf16 out)
  gemm_bt<false><<<dim3(640), 512, 0, stream>>>(hidden_bf, bt_qkv, qkv_raw, 8192, QKVW, 2048);
  // 3) fused: norm_rope + V-transpose + wo convert-transpose
  prep1<<<dim3(43008), 256, 0, stream>>>(qkv_raw, cosb, sinb, qnw, knw, k_f, vt, wo, bt_wo);
  // 4) causal flash attention + gating (paired q-tiles, uniform work)
  attn_kernel<<<dim3(8, NHEAD, NB), 512, 0, stream>>>(qkv_raw, k_f, vt, g_attn);
  // 5) output projection, fp32 store
  gemm_bt<true><<<dim3(256), 512, 0, stream>>>(g_attn, bt_wo, out, 8192, 2048, 2048);
}